// Round 7
// baseline (49.632 us; speedup 1.0000x reference)
//
#include <hip/hip_runtime.h>

#pragma clang fp contract(off)

#define HH 96
#define WW 96
#define KK 16
#define MM 2
#define NF 512            // M * Fm
#define NPIX (HH*WW)      // 9216
#define TDIM 12           // tiles per side
#define TSZ 8             // pixels per tile side
#define NTILE (TDIM*TDIM) // 144
#define MAXC 8            // max list chunks (NF/64)

#define SIGMA_F 1e-4f
#define GAMMA_F 1e-4f
#define BLUR_F  9.210240366975851e-4f   // log(1/1e-4 - 1) * 1e-4 -> f32
#define EPS_F   1e-10f
#define ZFAR_F  100.0f
#define ZNEAR_F 1.0f
#define RM      0.0304f                 // > sqrt(BLUR_F) = 0.0303484

#define SENT 0xFFFFFFFFFFFFFFFFull

__device__ __forceinline__ float frcp(float x) { return __builtin_amdgcn_rcpf(x); }

__device__ __forceinline__ float edge_d2(float px, float py,
                                         float ax, float ay,
                                         float bx, float by) {
    float abx = bx - ax, aby = by - ay;
    float apx = px - ax, apy = py - ay;
    float t = (apx*abx + apy*aby) * frcp(abx*abx + aby*aby + 1e-12f);
    t = fminf(fmaxf(t, 0.0f), 1.0f);
    float dx = apx - t*abx, dy = apy - t*aby;
    return dx*dx + dy*dy;
}

struct Rast { float b0, b1, b2, zpix, dists; };

// geo-packed layout: g0=(x0,y0,x1,y1) g1=(x2,y2,z0,z1) g2=(z2,-,-,-)
__device__ __forceinline__ Rast rasterize_g(float px, float py,
                                            float4 g0, float4 g1, float4 g2) {
    Rast r;
    float v0x=g0.x, v0y=g0.y, v1x=g0.z, v1y=g0.w, v2x=g1.x, v2y=g1.y;
    float z0=g1.z, z1=g1.w, z2=g2.x;
    float e1x=v1x-v0x, e1y=v1y-v0y, e2x=v2x-v0x, e2y=v2y-v0y;
    float dx=px-v0x, dy=py-v0y;
    float rden = frcp(e1x*e2y - e1y*e2x + 1e-12f);
    r.b1 = (dx*e2y - dy*e2x) * rden;
    r.b2 = (e1x*dy - e1y*dx) * rden;
    r.b0 = 1.0f - r.b1 - r.b2;
    r.zpix = r.b0*z0 + r.b1*z1 + r.b2*z2;
    bool inside = (r.b0 >= 0.0f) && (r.b1 >= 0.0f) && (r.b2 >= 0.0f);
    float d2 = edge_d2(px, py, v0x, v0y, v1x, v1y);
    d2 = fminf(d2, edge_d2(px, py, v1x, v1y, v2x, v2y));
    d2 = fminf(d2, edge_d2(px, py, v2x, v2y, v0x, v0y));
    r.dists = inside ? -d2 : d2;
    return r;
}

__device__ __forceinline__ unsigned long long packzf(float z, int f) {
    return (((unsigned long long)__float_as_uint(z)) << 32) | (unsigned int)f;
}

__device__ __forceinline__ unsigned long long shflx64(unsigned long long v, int m) {
    int lo = __shfl_xor((int)(unsigned)(v & 0xffffffffull), m, 64);
    int hi = __shfl_xor((int)(unsigned)(v >> 32), m, 64);
    return ((unsigned long long)(unsigned)hi << 32) | (unsigned)lo;
}

__device__ __forceinline__ void agg_face(float px, float py,
                                         const float4* __restrict__ geop,
                                         const float4* __restrict__ colp,
                                         int bf, float z, float zmaxv,
                                         float& nr, float& ng, float& nb,
                                         float& dn, float& ap) {
    float4 g0 = geop[bf*3+0], g1 = geop[bf*3+1], g2 = geop[bf*3+2];
    Rast r = rasterize_g(px, py, g0, g1, g2);
    float prob = frcp(1.0f + __expf(r.dists / SIGMA_F));
    float zinv = (ZFAR_F - z) / (ZFAR_F - ZNEAR_F);
    float w = prob * __expf((zinv - zmaxv) / GAMMA_F);
    float4 c0 = colp[bf*3+0], c1 = colp[bf*3+1], c2 = colp[bf*3+2];
    nr += w * (r.b0*c0.x + r.b1*c1.x + r.b2*c2.x);
    ng += w * (r.b0*c0.y + r.b1*c1.y + r.b2*c2.y);
    nb += w * (r.b0*c0.z + r.b1*c1.z + r.b2*c2.z);
    dn += w;
    ap *= (1.0f - prob);
}

// ============ kernel 1: stage per-(b,face) bbox/geo/col records ============
__global__ void stage_kernel(
    const float* __restrict__ mpos, const float* __restrict__ mrot,
    const float* __restrict__ mscale, const float* __restrict__ cpos,
    const float* __restrict__ crot, const float* __restrict__ verts,
    const int* __restrict__ faces, const float* __restrict__ vcol,
    float4* __restrict__ ws)
{
    const int b = blockIdx.x / MM, m = blockIdx.x % MM, t = threadIdx.x;
    const int B = gridDim.x / MM;
    const int BF = B * NF;
    __shared__ float sx[256], sy[256], sz[256];

    float cr[9];
    #pragma unroll
    for (int i = 0; i < 9; ++i) cr[i] = crot[b*9 + i];
    const float cpx = cpos[b*3+0], cpy = cpos[b*3+1], cpz = cpos[b*3+2];

    {
        int sb = (b*MM + m)*3, rb = (b*MM + m)*9;
        int vid = m*256 + t;
        float v0 = verts[vid*3+0] * mscale[sb+0];
        float v1 = verts[vid*3+1] * mscale[sb+1];
        float v2 = verts[vid*3+2] * mscale[sb+2];
        float wx = mrot[rb+0]*v0 + mrot[rb+1]*v1 + mrot[rb+2]*v2 + mpos[sb+0];
        float wy = mrot[rb+3]*v0 + mrot[rb+4]*v1 + mrot[rb+5]*v2 + mpos[sb+1];
        float wz = mrot[rb+6]*v0 + mrot[rb+7]*v1 + mrot[rb+8]*v2 + mpos[sb+2];
        float cx = wx*cr[0] + wy*cr[3] + wz*cr[6] + cpx;
        float cy = wx*cr[1] + wy*cr[4] + wz*cr[7] + cpy;
        float cz = wx*cr[2] + wy*cr[5] + wz*cr[8] + cpz;
        sx[t] = cx / cz;  sy[t] = cy / cz;  sz[t] = cz;
    }
    __syncthreads();

    const int fb = (m*256 + t)*3;
    const int i0 = faces[fb+0], i1 = faces[fb+1], i2 = faces[fb+2];
    const float x0 = sx[i0], y0 = sy[i0], z0 = sz[i0];
    const float x1 = sx[i1], y1 = sy[i1], z1 = sz[i1];
    const float x2 = sx[i2], y2 = sy[i2], z2 = sz[i2];

    const int bf = b*NF + m*256 + t;
    float4* bboxp = ws;
    float4* geop  = ws + BF;
    float4* colp  = ws + 4*BF;

    bboxp[bf] = make_float4(fminf(fminf(x0,x1),x2), fminf(fminf(y0,y1),y2),
                            fmaxf(fmaxf(x0,x1),x2), fmaxf(fmaxf(y0,y1),y2));
    geop[bf*3+0] = make_float4(x0, y0, x1, y1);
    geop[bf*3+1] = make_float4(x2, y2, z0, z1);
    geop[bf*3+2] = make_float4(z2, 0.0f, 0.0f, 0.0f);

    int c0i = (m*256 + i0)*3, c1i = (m*256 + i1)*3, c2i = (m*256 + i2)*3;
    colp[bf*3+0] = make_float4(vcol[c0i], vcol[c0i+1], vcol[c0i+2], 0.0f);
    colp[bf*3+1] = make_float4(vcol[c1i], vcol[c1i+1], vcol[c1i+2], 0.0f);
    colp[bf*3+2] = make_float4(vcol[c2i], vcol[c2i+1], vcol[c2i+2], 0.0f);
}

// ============ kernel 2: deterministic tile binning (1 wave per (b,tile)) ============
__global__ __launch_bounds__(256) void bin_kernel(
    const float4* __restrict__ ws, unsigned short* __restrict__ lists,
    int* __restrict__ cnts, int B)
{
    const int wid  = (blockIdx.x * 256 + threadIdx.x) >> 6;   // global wave id
    const int lane = threadIdx.x & 63;
    const int b = wid / NTILE, tile = wid % NTILE;
    const int ty = tile / TDIM, tx = tile % TDIM;
    const float x_lo = -1.0f + tx * (2.0f / TDIM);
    const float x_hi = x_lo + 2.0f / TDIM;
    const float y_hi = 1.0f - ty * (2.0f / TDIM);
    const float y_lo = y_hi - 2.0f / TDIM;

    const float4* bboxp = ws;
    unsigned short* list = lists + (size_t)wid * NF;
    int base = 0;
    #pragma unroll
    for (int k = 0; k < 8; ++k) {
        int f = (k << 6) | lane;
        float4 bb = bboxp[b*NF + f];
        bool hit = (bb.x - RM <= x_hi) && (bb.z + RM >= x_lo) &&
                   (bb.y - RM <= y_hi) && (bb.w + RM >= y_lo);
        unsigned long long m = __ballot(hit);
        if (hit) {
            int rank = __popcll(m & ((1ull << lane) - 1ull));
            list[base + rank] = (unsigned short)f;
        }
        base += __popcll(m);
    }
    if (lane == 0) cnts[wid] = base;
}

// ============ kernel 3: wave-per-pixel render over binned lists ============
__global__ __launch_bounds__(512) void render_tile_kernel(
    const float4* __restrict__ ws, const unsigned short* __restrict__ lists,
    const int* __restrict__ cnts, float* __restrict__ out, int B)
{
    const int wv   = threadIdx.x >> 6;              // 0..7
    const int lane = threadIdx.x & 63;
    const int blocksPerB = NTILE * 8;               // 8 blocks per tile (8 px each)
    const int b    = blockIdx.x / blocksPerB;
    const int rem  = blockIdx.x % blocksPerB;
    const int tile = rem >> 3, q = rem & 7;
    const int pit  = q * 8 + wv;                    // pixel-in-tile 0..63
    const int ty = tile / TDIM, tx = tile % TDIM;
    const int pi = ty * TSZ + (pit >> 3), pj = tx * TSZ + (pit & 7);
    const float px = ((float)pj + 0.5f) * (2.0f / WW) - 1.0f;
    const float py = 1.0f - ((float)pi + 0.5f) * (2.0f / HH);

    const int BF = B * NF;
    const float4* geop = ws + BF;
    const float4* colp = ws + 4*BF;
    const unsigned short* list = lists + (size_t)(b*NTILE + tile) * NF;
    const int L = cnts[b*NTILE + tile];
    const int base = b * NF;

    // ---- scan the tile's list: static chunk slots ----
    unsigned long long pk[MAXC];
    int validm = 0;
    #pragma unroll
    for (int c = 0; c < MAXC; ++c) {
        pk[c] = SENT;
        if (c * 64 < L) {                            // wave-uniform guard
            int idx = c * 64 + lane;
            unsigned long long t = SENT;
            if (idx < L) {
                int f  = list[idx];
                int bf = base + f;
                float4 g0 = geop[bf*3+0], g1 = geop[bf*3+1], g2 = geop[bf*3+2];
                Rast r = rasterize_g(px, py, g0, g1, g2);
                if (r.zpix > 0.01f && r.dists <= BLUR_F) t = packzf(r.zpix, f);
            }
            pk[c] = t;
            validm |= (t != SENT ? 1 : 0) << c;
        }
    }

    const int c0 = __popc(validm);
    int cnt = c0;
    #pragma unroll
    for (int m = 1; m < 64; m <<= 1) cnt += __shfl_xor(cnt, m, 64);

    float nr = 0.0f, ng = 0.0f, nb = 0.0f, dn = 0.0f, ap = 1.0f;
    float zmaxv = EPS_F;

    if (cnt <= KK) {
        // ---- common path: all candidates included; zmax from butterfly min ----
        unsigned long long lmin = pk[0];
        #pragma unroll
        for (int c = 1; c < MAXC; ++c) lmin = (pk[c] < lmin) ? pk[c] : lmin;
        #pragma unroll
        for (int m = 1; m < 64; m <<= 1) {
            unsigned long long o2 = shflx64(lmin, m);
            lmin = (o2 < lmin) ? o2 : lmin;
        }
        if (cnt > 0) {
            float zming = __uint_as_float((unsigned)(lmin >> 32));
            zmaxv = fmaxf((ZFAR_F - zming) / (ZFAR_F - ZNEAR_F), EPS_F);
        }
        #pragma unroll
        for (int c = 0; c < MAXC; ++c)
            if (validm & (1 << c)) {
                int f = (int)(pk[c] & 0xffffffffull);
                float z = __uint_as_float((unsigned)(pk[c] >> 32));
                agg_face(px, py, geop, colp, base + f, z, zmaxv, nr, ng, nb, dn, ap);
            }
    } else if (L <= 64) {
        // ---- single-chunk sort path: bitonic ascending on registers ----
        unsigned long long v = pk[0];
        #pragma unroll
        for (int kk = 2; kk <= 64; kk <<= 1) {
            #pragma unroll
            for (int j = kk >> 1; j > 0; j >>= 1) {
                unsigned long long o2 = shflx64(v, j);
                bool kmin = ((lane & kk) == 0) == ((lane & j) == 0);
                v = (kmin == (o2 < v)) ? o2 : v;
            }
        }
        unsigned z0b = (unsigned)__shfl((int)(unsigned)(v >> 32), 0, 64);
        zmaxv = fmaxf((ZFAR_F - __uint_as_float(z0b)) / (ZFAR_F - ZNEAR_F), EPS_F);
        if (lane < KK) {                             // cnt > 16 => all 16 valid
            int f = (int)(v & 0xffffffffull);
            float z = __uint_as_float((unsigned)(v >> 32));
            agg_face(px, py, geop, colp, base + f, z, zmaxv, nr, ng, nb, dn, ap);
        }
    } else {
        // ---- rare: multi-chunk & cnt>16 -> pop-min 16 rounds ----
        int remm = validm, inclm = 0;
        float zming = 0.0f;
        for (int r = 0; r < KK; ++r) {
            unsigned long long lm = SENT;
            #pragma unroll
            for (int k = 0; k < MAXC; ++k)
                if (remm & (1 << k)) lm = (pk[k] < lm) ? pk[k] : lm;
            #pragma unroll
            for (int m = 1; m < 64; m <<= 1) {
                unsigned long long o2 = shflx64(lm, m);
                lm = (o2 < lm) ? o2 : lm;
            }
            if (r == 0) zming = __uint_as_float((unsigned)(lm >> 32));
            #pragma unroll
            for (int k = 0; k < MAXC; ++k)
                if ((remm & (1 << k)) && pk[k] == lm) { inclm |= 1 << k; remm &= ~(1 << k); }
        }
        zmaxv = fmaxf((ZFAR_F - zming) / (ZFAR_F - ZNEAR_F), EPS_F);
        #pragma unroll
        for (int k = 0; k < MAXC; ++k)
            if (inclm & (1 << k)) {
                int f = (int)(pk[k] & 0xffffffffull);
                float z = __uint_as_float((unsigned)(pk[k] >> 32));
                agg_face(px, py, geop, colp, base + f, z, zmaxv, nr, ng, nb, dn, ap);
            }
    }

    // ---- wave butterfly reductions (deterministic fixed order) ----
    #pragma unroll
    for (int m = 1; m < 64; m <<= 1) {
        nr += __shfl_xor(nr, m, 64);
        ng += __shfl_xor(ng, m, 64);
        nb += __shfl_xor(nb, m, 64);
        dn += __shfl_xor(dn, m, 64);
        ap *= __shfl_xor(ap, m, 64);
    }
    if (lane == 0) {
        float delta = __expf((EPS_F - zmaxv) / GAMMA_F);
        float dd = dn + delta;
        float4 o4;
        o4.x = (nr + delta) / dd;
        o4.y = (ng + delta) / dd;
        o4.z = (nb + delta) / dd;
        o4.w = 1.0f - ap;
        *reinterpret_cast<float4*>(&out[((size_t)b * NPIX + pi * WW + pj) * 4]) = o4;
    }
}

// ============ fallback: round-6 wave-per-pixel kernel (no binning) ============
__global__ __launch_bounds__(256) void render_wave_kernel(
    const float4* __restrict__ ws, float* __restrict__ out, int B)
{
    const int tilesPerB = NPIX / 4;
    const int b    = blockIdx.x / tilesPerB;
    const int tile = blockIdx.x % tilesPerB;
    const int wv   = threadIdx.x >> 6;
    const int lane = threadIdx.x & 63;
    const int p    = tile*4 + wv;
    const int pi = p / WW, pj = p % WW;
    const float px = ((float)pj + 0.5f) * 2.0f / (float)WW - 1.0f;
    const float py = 1.0f - ((float)pi + 0.5f) * 2.0f / (float)HH;

    const int BF = B * NF;
    const float4* bboxp = ws;
    const float4* geop  = ws + BF;
    const float4* colp  = ws + 4*BF;
    const int base = b * NF;

    unsigned long long pk[8];
    int validm = 0;
    #pragma unroll
    for (int k = 0; k < 8; ++k) {
        int f  = (k << 6) | lane;
        int bf = base + f;
        float4 bb = bboxp[bf];
        unsigned long long t = SENT;
        if (px >= bb.x - RM && px <= bb.z + RM &&
            py >= bb.y - RM && py <= bb.w + RM) {
            float4 g0 = geop[bf*3+0], g1 = geop[bf*3+1], g2 = geop[bf*3+2];
            Rast r = rasterize_g(px, py, g0, g1, g2);
            if (r.zpix > 0.01f && r.dists <= BLUR_F) t = packzf(r.zpix, f);
        }
        pk[k] = t;
        validm |= (t != SENT ? 1 : 0) << k;
    }

    const int c0 = __popc(validm);
    int cnt = c0;
    #pragma unroll
    for (int m = 1; m < 64; m <<= 1) cnt += __shfl_xor(cnt, m, 64);

    float nr = 0.0f, ng = 0.0f, nb = 0.0f, dn = 0.0f, ap = 1.0f;
    float zmaxv = EPS_F;

    if (cnt <= KK) {
        unsigned long long lmin = pk[0];
        #pragma unroll
        for (int c = 1; c < 8; ++c) lmin = (pk[c] < lmin) ? pk[c] : lmin;
        #pragma unroll
        for (int m = 1; m < 64; m <<= 1) {
            unsigned long long o2 = shflx64(lmin, m);
            lmin = (o2 < lmin) ? o2 : lmin;
        }
        if (cnt > 0) {
            float zming = __uint_as_float((unsigned)(lmin >> 32));
            zmaxv = fmaxf((ZFAR_F - zming) / (ZFAR_F - ZNEAR_F), EPS_F);
        }
        #pragma unroll
        for (int c = 0; c < 8; ++c)
            if (validm & (1 << c)) {
                int f = (int)(pk[c] & 0xffffffffull);
                float z = __uint_as_float((unsigned)(pk[c] >> 32));
                agg_face(px, py, geop, colp, base + f, z, zmaxv, nr, ng, nb, dn, ap);
            }
    } else {
        int remm = validm, inclm = 0;
        float zming = 0.0f;
        for (int r = 0; r < KK; ++r) {
            unsigned long long lm = SENT;
            #pragma unroll
            for (int k = 0; k < 8; ++k)
                if (remm & (1 << k)) lm = (pk[k] < lm) ? pk[k] : lm;
            #pragma unroll
            for (int m = 1; m < 64; m <<= 1) {
                unsigned long long o2 = shflx64(lm, m);
                lm = (o2 < lm) ? o2 : lm;
            }
            if (r == 0) zming = __uint_as_float((unsigned)(lm >> 32));
            #pragma unroll
            for (int k = 0; k < 8; ++k)
                if ((remm & (1 << k)) && pk[k] == lm) { inclm |= 1 << k; remm &= ~(1 << k); }
        }
        zmaxv = fmaxf((ZFAR_F - zming) / (ZFAR_F - ZNEAR_F), EPS_F);
        #pragma unroll
        for (int k = 0; k < 8; ++k)
            if (inclm & (1 << k)) {
                int f = (int)(pk[k] & 0xffffffffull);
                float z = __uint_as_float((unsigned)(pk[k] >> 32));
                agg_face(px, py, geop, colp, base + f, z, zmaxv, nr, ng, nb, dn, ap);
            }
    }

    #pragma unroll
    for (int m = 1; m < 64; m <<= 1) {
        nr += __shfl_xor(nr, m, 64);
        ng += __shfl_xor(ng, m, 64);
        nb += __shfl_xor(nb, m, 64);
        dn += __shfl_xor(dn, m, 64);
        ap *= __shfl_xor(ap, m, 64);
    }
    if (lane == 0) {
        float delta = __expf((EPS_F - zmaxv) / GAMMA_F);
        float dd = dn + delta;
        float4 o4;
        o4.x = (nr + delta) / dd;
        o4.y = (ng + delta) / dd;
        o4.z = (nb + delta) / dd;
        o4.w = 1.0f - ap;
        *reinterpret_cast<float4*>(&out[((size_t)b * NPIX + p) * 4]) = o4;
    }
}

extern "C" void kernel_launch(void* const* d_in, const int* in_sizes, int n_in,
                              void* d_out, int out_size, void* d_ws, size_t ws_size,
                              hipStream_t stream) {
    const float* mpos   = (const float*)d_in[0];
    const float* mrot   = (const float*)d_in[1];
    const float* mscale = (const float*)d_in[2];
    const float* cpos   = (const float*)d_in[3];
    const float* crot   = (const float*)d_in[4];
    const float* verts  = (const float*)d_in[5];
    const int*   faces  = (const int*)d_in[6];
    const float* vcol   = (const float*)d_in[7];
    float*       out    = (float*)d_out;

    const int B  = in_sizes[3] / 3;                 // cam_pos is (B,3)
    const int BF = B * NF;
    const size_t base_bytes  = (size_t)BF * 7 * sizeof(float4);      // bbox+geo+col
    const size_t lists_bytes = (size_t)B * NTILE * NF * sizeof(unsigned short);
    const size_t cnts_bytes  = (size_t)B * NTILE * sizeof(int);
    const size_t need_full   = base_bytes + lists_bytes + cnts_bytes;

    float4* wsf = (float4*)d_ws;
    if (ws_size >= need_full) {
        unsigned short* lists = (unsigned short*)((char*)d_ws + base_bytes);
        int* cnts = (int*)((char*)d_ws + base_bytes + lists_bytes);
        stage_kernel<<<dim3(B * MM), dim3(256), 0, stream>>>(
            mpos, mrot, mscale, cpos, crot, verts, faces, vcol, wsf);
        bin_kernel<<<dim3((B * NTILE) / 4), dim3(256), 0, stream>>>(
            wsf, lists, cnts, B);
        render_tile_kernel<<<dim3(B * NTILE * 8), dim3(512), 0, stream>>>(
            wsf, lists, cnts, out, B);
    } else {
        stage_kernel<<<dim3(B * MM), dim3(256), 0, stream>>>(
            mpos, mrot, mscale, cpos, crot, verts, faces, vcol, wsf);
        render_wave_kernel<<<dim3(B * (NPIX / 4)), dim3(256), 0, stream>>>(
            wsf, out, B);
    }
}

// Round 8
// 45.550 us; speedup vs baseline: 1.0896x; 1.0896x over previous
//
#include <hip/hip_runtime.h>

#pragma clang fp contract(off)

#define HH 96
#define WW 96
#define KK 16
#define MM 2
#define NF 512            // M * Fm
#define NPIX (HH*WW)      // 9216
#define TDIM 12           // tiles per side
#define TSZ 8             // pixels per tile side
#define NTILE (TDIM*TDIM) // 144
#define MAXC 8            // max list chunks (NF/64)

#define SIGMA_F 1e-4f
#define GAMMA_F 1e-4f
#define BLUR_F  9.210240366975851e-4f   // log(1/1e-4 - 1) * 1e-4 -> f32
#define EPS_F   1e-10f
#define ZFAR_F  100.0f
#define ZNEAR_F 1.0f
#define RM      0.0304f                 // > sqrt(BLUR_F) = 0.0303484

#define SENT 0xFFFFFFFFFFFFFFFFull

__device__ __forceinline__ float frcp(float x) { return __builtin_amdgcn_rcpf(x); }

__device__ __forceinline__ float edge_d2(float px, float py,
                                         float ax, float ay,
                                         float bx, float by) {
    float abx = bx - ax, aby = by - ay;
    float apx = px - ax, apy = py - ay;
    float t = (apx*abx + apy*aby) * frcp(abx*abx + aby*aby + 1e-12f);
    t = fminf(fmaxf(t, 0.0f), 1.0f);
    float dx = apx - t*abx, dy = apy - t*aby;
    return dx*dx + dy*dy;
}

struct Rast { float b0, b1, b2, zpix, dists; };

// geo-packed layout: g0=(x0,y0,x1,y1) g1=(x2,y2,z0,z1) g2=(z2,-,-,-)
__device__ __forceinline__ Rast rasterize_g(float px, float py,
                                            float4 g0, float4 g1, float4 g2) {
    Rast r;
    float v0x=g0.x, v0y=g0.y, v1x=g0.z, v1y=g0.w, v2x=g1.x, v2y=g1.y;
    float z0=g1.z, z1=g1.w, z2=g2.x;
    float e1x=v1x-v0x, e1y=v1y-v0y, e2x=v2x-v0x, e2y=v2y-v0y;
    float dx=px-v0x, dy=py-v0y;
    float rden = frcp(e1x*e2y - e1y*e2x + 1e-12f);
    r.b1 = (dx*e2y - dy*e2x) * rden;
    r.b2 = (e1x*dy - e1y*dx) * rden;
    r.b0 = 1.0f - r.b1 - r.b2;
    r.zpix = r.b0*z0 + r.b1*z1 + r.b2*z2;
    bool inside = (r.b0 >= 0.0f) && (r.b1 >= 0.0f) && (r.b2 >= 0.0f);
    float d2 = edge_d2(px, py, v0x, v0y, v1x, v1y);
    d2 = fminf(d2, edge_d2(px, py, v1x, v1y, v2x, v2y));
    d2 = fminf(d2, edge_d2(px, py, v2x, v2y, v0x, v0y));
    r.dists = inside ? -d2 : d2;
    return r;
}

__device__ __forceinline__ unsigned long long packzf(float z, int f) {
    return (((unsigned long long)__float_as_uint(z)) << 32) | (unsigned int)f;
}

__device__ __forceinline__ unsigned long long shflx64(unsigned long long v, int m) {
    int lo = __shfl_xor((int)(unsigned)(v & 0xffffffffull), m, 64);
    int hi = __shfl_xor((int)(unsigned)(v >> 32), m, 64);
    return ((unsigned long long)(unsigned)hi << 32) | (unsigned)lo;
}

__device__ __forceinline__ void agg_face(float px, float py,
                                         const float4* __restrict__ geop,
                                         const float4* __restrict__ colp,
                                         int bf, float z, float zmaxv,
                                         float& nr, float& ng, float& nb,
                                         float& dn, float& ap) {
    // issue all 6 loads up front (independent) so they overlap the math
    float4 g0 = geop[bf*3+0], g1 = geop[bf*3+1], g2 = geop[bf*3+2];
    float4 c0 = colp[bf*3+0], c1 = colp[bf*3+1], c2 = colp[bf*3+2];
    Rast r = rasterize_g(px, py, g0, g1, g2);
    float prob = frcp(1.0f + __expf(r.dists / SIGMA_F));
    float zinv = (ZFAR_F - z) / (ZFAR_F - ZNEAR_F);
    float w = prob * __expf((zinv - zmaxv) / GAMMA_F);
    nr += w * (r.b0*c0.x + r.b1*c1.x + r.b2*c2.x);
    ng += w * (r.b0*c0.y + r.b1*c1.y + r.b2*c2.y);
    nb += w * (r.b0*c0.z + r.b1*c1.z + r.b2*c2.z);
    dn += w;
    ap *= (1.0f - prob);
}

// ============ kernel 1: stage per-(b,face) bbox/geo/col records ============
__global__ void stage_kernel(
    const float* __restrict__ mpos, const float* __restrict__ mrot,
    const float* __restrict__ mscale, const float* __restrict__ cpos,
    const float* __restrict__ crot, const float* __restrict__ verts,
    const int* __restrict__ faces, const float* __restrict__ vcol,
    float4* __restrict__ ws)
{
    const int b = blockIdx.x / MM, m = blockIdx.x % MM, t = threadIdx.x;
    const int B = gridDim.x / MM;
    const int BF = B * NF;
    __shared__ float sx[256], sy[256], sz[256];

    float cr[9];
    #pragma unroll
    for (int i = 0; i < 9; ++i) cr[i] = crot[b*9 + i];
    const float cpx = cpos[b*3+0], cpy = cpos[b*3+1], cpz = cpos[b*3+2];

    {
        int sb = (b*MM + m)*3, rb = (b*MM + m)*9;
        int vid = m*256 + t;
        float v0 = verts[vid*3+0] * mscale[sb+0];
        float v1 = verts[vid*3+1] * mscale[sb+1];
        float v2 = verts[vid*3+2] * mscale[sb+2];
        float wx = mrot[rb+0]*v0 + mrot[rb+1]*v1 + mrot[rb+2]*v2 + mpos[sb+0];
        float wy = mrot[rb+3]*v0 + mrot[rb+4]*v1 + mrot[rb+5]*v2 + mpos[sb+1];
        float wz = mrot[rb+6]*v0 + mrot[rb+7]*v1 + mrot[rb+8]*v2 + mpos[sb+2];
        float cx = wx*cr[0] + wy*cr[3] + wz*cr[6] + cpx;
        float cy = wx*cr[1] + wy*cr[4] + wz*cr[7] + cpy;
        float cz = wx*cr[2] + wy*cr[5] + wz*cr[8] + cpz;
        sx[t] = cx / cz;  sy[t] = cy / cz;  sz[t] = cz;
    }
    __syncthreads();

    const int fb = (m*256 + t)*3;
    const int i0 = faces[fb+0], i1 = faces[fb+1], i2 = faces[fb+2];
    const float x0 = sx[i0], y0 = sy[i0], z0 = sz[i0];
    const float x1 = sx[i1], y1 = sy[i1], z1 = sz[i1];
    const float x2 = sx[i2], y2 = sy[i2], z2 = sz[i2];

    const int bf = b*NF + m*256 + t;
    float4* bboxp = ws;
    float4* geop  = ws + BF;
    float4* colp  = ws + 4*BF;

    bboxp[bf] = make_float4(fminf(fminf(x0,x1),x2), fminf(fminf(y0,y1),y2),
                            fmaxf(fmaxf(x0,x1),x2), fmaxf(fmaxf(y0,y1),y2));
    geop[bf*3+0] = make_float4(x0, y0, x1, y1);
    geop[bf*3+1] = make_float4(x2, y2, z0, z1);
    geop[bf*3+2] = make_float4(z2, 0.0f, 0.0f, 0.0f);

    int c0i = (m*256 + i0)*3, c1i = (m*256 + i1)*3, c2i = (m*256 + i2)*3;
    colp[bf*3+0] = make_float4(vcol[c0i], vcol[c0i+1], vcol[c0i+2], 0.0f);
    colp[bf*3+1] = make_float4(vcol[c1i], vcol[c1i+1], vcol[c1i+2], 0.0f);
    colp[bf*3+2] = make_float4(vcol[c2i], vcol[c2i+1], vcol[c2i+2], 0.0f);
}

// ============ kernel 2: deterministic tile binning (1 wave per (b,tile)) ============
__global__ __launch_bounds__(256) void bin_kernel(
    const float4* __restrict__ ws, unsigned short* __restrict__ lists,
    int* __restrict__ cnts, int B)
{
    const int wid  = (blockIdx.x * 256 + threadIdx.x) >> 6;   // global wave id
    const int lane = threadIdx.x & 63;
    const int b = wid / NTILE, tile = wid % NTILE;
    const int ty = tile / TDIM, tx = tile % TDIM;
    const float x_lo = -1.0f + tx * (2.0f / TDIM);
    const float x_hi = x_lo + 2.0f / TDIM;
    const float y_hi = 1.0f - ty * (2.0f / TDIM);
    const float y_lo = y_hi - 2.0f / TDIM;

    const float4* bboxp = ws;
    unsigned short* list = lists + (size_t)wid * NF;
    int base = 0;
    #pragma unroll
    for (int k = 0; k < 8; ++k) {
        int f = (k << 6) | lane;
        float4 bb = bboxp[b*NF + f];
        bool hit = (bb.x - RM <= x_hi) && (bb.z + RM >= x_lo) &&
                   (bb.y - RM <= y_hi) && (bb.w + RM >= y_lo);
        unsigned long long m = __ballot(hit);
        if (hit) {
            int rank = __popcll(m & ((1ull << lane) - 1ull));
            list[base + rank] = (unsigned short)f;
        }
        base += __popcll(m);
    }
    if (lane == 0) cnts[wid] = base;
}

// ============ kernel 3: wave-per-pixel render, software-pipelined scan ============
__global__ __launch_bounds__(256) void render_tile_kernel(
    const float4* __restrict__ ws, const unsigned short* __restrict__ lists,
    const int* __restrict__ cnts, float* __restrict__ out, int B)
{
    const int wv   = threadIdx.x >> 6;              // 0..3
    const int lane = threadIdx.x & 63;
    const int blocksPerB = NTILE * 16;              // 16 blocks per tile (4 px each)
    const int b    = blockIdx.x / blocksPerB;
    const int rem  = blockIdx.x % blocksPerB;
    const int tile = rem >> 4, q = rem & 15;
    const int pit  = q * 4 + wv;                    // pixel-in-tile 0..63
    const int ty = tile / TDIM, tx = tile % TDIM;
    const int pi = ty * TSZ + (pit >> 3), pj = tx * TSZ + (pit & 7);
    const float px = ((float)pj + 0.5f) * (2.0f / WW) - 1.0f;
    const float py = 1.0f - ((float)pi + 0.5f) * (2.0f / HH);

    const int BF = B * NF;
    const float4* geop = ws + BF;
    const float4* colp = ws + 4*BF;
    const unsigned short* list = lists + (size_t)(b*NTILE + tile) * NF;
    const int L = cnts[b*NTILE + tile];
    const int base = b * NF;

    // ---- prefetch ALL list chunks upfront (independent loads, one wait) ----
    int fid[MAXC];
    #pragma unroll
    for (int c = 0; c < MAXC; ++c) {
        fid[c] = -1;
        if (c * 64 < L) {                            // wave-uniform guard
            int idx = c * 64 + lane;
            if (idx < L) fid[c] = (int)list[idx];
        }
    }

    // ---- scan with double-buffered geo prefetch (named A/B regs, static) ----
    unsigned long long pk[MAXC];
    int validm = 0;
    float4 gA0, gA1, gA2, gB0, gB1, gB2;

#define GLOAD(c, G0, G1, G2) do { \
        int bf3_ = (base + ((fid[(c)] < 0) ? 0 : fid[(c)])) * 3; \
        G0 = geop[bf3_+0]; G1 = geop[bf3_+1]; G2 = geop[bf3_+2]; \
    } while (0)

#define PROC(c, G0, G1, G2) do { \
        unsigned long long t_ = SENT; \
        if (fid[(c)] >= 0) { \
            Rast r_ = rasterize_g(px, py, G0, G1, G2); \
            if (r_.zpix > 0.01f && r_.dists <= BLUR_F) t_ = packzf(r_.zpix, fid[(c)]); \
        } \
        pk[(c)] = t_; \
        validm |= (t_ != SENT ? 1 : 0) << (c); \
    } while (0)

    if (0 * 64 < L) GLOAD(0, gA0, gA1, gA2);
    #pragma unroll
    for (int c = 0; c < MAXC; ++c) {
        pk[c] = SENT;
        if (c * 64 < L) {                            // wave-uniform
            if ((c & 1) == 0) {
                if (c + 1 < MAXC && (c + 1) * 64 < L) GLOAD(c + 1, gB0, gB1, gB2);
                PROC(c, gA0, gA1, gA2);
            } else {
                if (c + 1 < MAXC && (c + 1) * 64 < L) GLOAD(c + 1, gA0, gA1, gA2);
                PROC(c, gB0, gB1, gB2);
            }
        }
    }
#undef GLOAD
#undef PROC

    const int c0 = __popc(validm);
    int cnt = c0;
    #pragma unroll
    for (int m = 1; m < 64; m <<= 1) cnt += __shfl_xor(cnt, m, 64);

    float nr = 0.0f, ng = 0.0f, nb = 0.0f, dn = 0.0f, ap = 1.0f;
    float zmaxv = EPS_F;

    if (cnt <= KK) {
        // ---- common path: all candidates included; zmax from butterfly min ----
        unsigned long long lmin = pk[0];
        #pragma unroll
        for (int c = 1; c < MAXC; ++c) lmin = (pk[c] < lmin) ? pk[c] : lmin;
        #pragma unroll
        for (int m = 1; m < 64; m <<= 1) {
            unsigned long long o2 = shflx64(lmin, m);
            lmin = (o2 < lmin) ? o2 : lmin;
        }
        if (cnt > 0) {
            float zming = __uint_as_float((unsigned)(lmin >> 32));
            zmaxv = fmaxf((ZFAR_F - zming) / (ZFAR_F - ZNEAR_F), EPS_F);
        }
        #pragma unroll
        for (int c = 0; c < MAXC; ++c)
            if (validm & (1 << c)) {
                int f = (int)(pk[c] & 0xffffffffull);
                float z = __uint_as_float((unsigned)(pk[c] >> 32));
                agg_face(px, py, geop, colp, base + f, z, zmaxv, nr, ng, nb, dn, ap);
            }
    } else if (L <= 64) {
        // ---- single-chunk sort path: bitonic ascending on registers ----
        unsigned long long v = pk[0];
        #pragma unroll
        for (int kk = 2; kk <= 64; kk <<= 1) {
            #pragma unroll
            for (int j = kk >> 1; j > 0; j >>= 1) {
                unsigned long long o2 = shflx64(v, j);
                bool kmin = ((lane & kk) == 0) == ((lane & j) == 0);
                v = (kmin == (o2 < v)) ? o2 : v;
            }
        }
        unsigned z0b = (unsigned)__shfl((int)(unsigned)(v >> 32), 0, 64);
        zmaxv = fmaxf((ZFAR_F - __uint_as_float(z0b)) / (ZFAR_F - ZNEAR_F), EPS_F);
        if (lane < KK) {                             // cnt > 16 => all 16 valid
            int f = (int)(v & 0xffffffffull);
            float z = __uint_as_float((unsigned)(v >> 32));
            agg_face(px, py, geop, colp, base + f, z, zmaxv, nr, ng, nb, dn, ap);
        }
    } else {
        // ---- multi-chunk & cnt>16 -> pop-min 16 rounds ----
        int remm = validm, inclm = 0;
        float zming = 0.0f;
        for (int r = 0; r < KK; ++r) {
            unsigned long long lm = SENT;
            #pragma unroll
            for (int k = 0; k < MAXC; ++k)
                if (remm & (1 << k)) lm = (pk[k] < lm) ? pk[k] : lm;
            #pragma unroll
            for (int m = 1; m < 64; m <<= 1) {
                unsigned long long o2 = shflx64(lm, m);
                lm = (o2 < lm) ? o2 : lm;
            }
            if (r == 0) zming = __uint_as_float((unsigned)(lm >> 32));
            #pragma unroll
            for (int k = 0; k < MAXC; ++k)
                if ((remm & (1 << k)) && pk[k] == lm) { inclm |= 1 << k; remm &= ~(1 << k); }
        }
        zmaxv = fmaxf((ZFAR_F - zming) / (ZFAR_F - ZNEAR_F), EPS_F);
        #pragma unroll
        for (int k = 0; k < MAXC; ++k)
            if (inclm & (1 << k)) {
                int f = (int)(pk[k] & 0xffffffffull);
                float z = __uint_as_float((unsigned)(pk[k] >> 32));
                agg_face(px, py, geop, colp, base + f, z, zmaxv, nr, ng, nb, dn, ap);
            }
    }

    // ---- wave butterfly reductions (deterministic fixed order) ----
    #pragma unroll
    for (int m = 1; m < 64; m <<= 1) {
        nr += __shfl_xor(nr, m, 64);
        ng += __shfl_xor(ng, m, 64);
        nb += __shfl_xor(nb, m, 64);
        dn += __shfl_xor(dn, m, 64);
        ap *= __shfl_xor(ap, m, 64);
    }
    if (lane == 0) {
        float delta = __expf((EPS_F - zmaxv) / GAMMA_F);
        float dd = dn + delta;
        float4 o4;
        o4.x = (nr + delta) / dd;
        o4.y = (ng + delta) / dd;
        o4.z = (nb + delta) / dd;
        o4.w = 1.0f - ap;
        *reinterpret_cast<float4*>(&out[((size_t)b * NPIX + pi * WW + pj) * 4]) = o4;
    }
}

// ============ fallback: round-6 wave-per-pixel kernel (no binning) ============
__global__ __launch_bounds__(256) void render_wave_kernel(
    const float4* __restrict__ ws, float* __restrict__ out, int B)
{
    const int tilesPerB = NPIX / 4;
    const int b    = blockIdx.x / tilesPerB;
    const int tile = blockIdx.x % tilesPerB;
    const int wv   = threadIdx.x >> 6;
    const int lane = threadIdx.x & 63;
    const int p    = tile*4 + wv;
    const int pi = p / WW, pj = p % WW;
    const float px = ((float)pj + 0.5f) * 2.0f / (float)WW - 1.0f;
    const float py = 1.0f - ((float)pi + 0.5f) * 2.0f / (float)HH;

    const int BF = B * NF;
    const float4* bboxp = ws;
    const float4* geop  = ws + BF;
    const float4* colp  = ws + 4*BF;
    const int base = b * NF;

    unsigned long long pk[8];
    int validm = 0;
    #pragma unroll
    for (int k = 0; k < 8; ++k) {
        int f  = (k << 6) | lane;
        int bf = base + f;
        float4 bb = bboxp[bf];
        unsigned long long t = SENT;
        if (px >= bb.x - RM && px <= bb.z + RM &&
            py >= bb.y - RM && py <= bb.w + RM) {
            float4 g0 = geop[bf*3+0], g1 = geop[bf*3+1], g2 = geop[bf*3+2];
            Rast r = rasterize_g(px, py, g0, g1, g2);
            if (r.zpix > 0.01f && r.dists <= BLUR_F) t = packzf(r.zpix, f);
        }
        pk[k] = t;
        validm |= (t != SENT ? 1 : 0) << k;
    }

    const int c0 = __popc(validm);
    int cnt = c0;
    #pragma unroll
    for (int m = 1; m < 64; m <<= 1) cnt += __shfl_xor(cnt, m, 64);

    float nr = 0.0f, ng = 0.0f, nb = 0.0f, dn = 0.0f, ap = 1.0f;
    float zmaxv = EPS_F;

    if (cnt <= KK) {
        unsigned long long lmin = pk[0];
        #pragma unroll
        for (int c = 1; c < 8; ++c) lmin = (pk[c] < lmin) ? pk[c] : lmin;
        #pragma unroll
        for (int m = 1; m < 64; m <<= 1) {
            unsigned long long o2 = shflx64(lmin, m);
            lmin = (o2 < lmin) ? o2 : lmin;
        }
        if (cnt > 0) {
            float zming = __uint_as_float((unsigned)(lmin >> 32));
            zmaxv = fmaxf((ZFAR_F - zming) / (ZFAR_F - ZNEAR_F), EPS_F);
        }
        #pragma unroll
        for (int c = 0; c < 8; ++c)
            if (validm & (1 << c)) {
                int f = (int)(pk[c] & 0xffffffffull);
                float z = __uint_as_float((unsigned)(pk[c] >> 32));
                agg_face(px, py, geop, colp, base + f, z, zmaxv, nr, ng, nb, dn, ap);
            }
    } else {
        int remm = validm, inclm = 0;
        float zming = 0.0f;
        for (int r = 0; r < KK; ++r) {
            unsigned long long lm = SENT;
            #pragma unroll
            for (int k = 0; k < 8; ++k)
                if (remm & (1 << k)) lm = (pk[k] < lm) ? pk[k] : lm;
            #pragma unroll
            for (int m = 1; m < 64; m <<= 1) {
                unsigned long long o2 = shflx64(lm, m);
                lm = (o2 < lm) ? o2 : lm;
            }
            if (r == 0) zming = __uint_as_float((unsigned)(lm >> 32));
            #pragma unroll
            for (int k = 0; k < 8; ++k)
                if ((remm & (1 << k)) && pk[k] == lm) { inclm |= 1 << k; remm &= ~(1 << k); }
        }
        zmaxv = fmaxf((ZFAR_F - zming) / (ZFAR_F - ZNEAR_F), EPS_F);
        #pragma unroll
        for (int k = 0; k < 8; ++k)
            if (inclm & (1 << k)) {
                int f = (int)(pk[k] & 0xffffffffull);
                float z = __uint_as_float((unsigned)(pk[k] >> 32));
                agg_face(px, py, geop, colp, base + f, z, zmaxv, nr, ng, nb, dn, ap);
            }
    }

    #pragma unroll
    for (int m = 1; m < 64; m <<= 1) {
        nr += __shfl_xor(nr, m, 64);
        ng += __shfl_xor(ng, m, 64);
        nb += __shfl_xor(nb, m, 64);
        dn += __shfl_xor(dn, m, 64);
        ap *= __shfl_xor(ap, m, 64);
    }
    if (lane == 0) {
        float delta = __expf((EPS_F - zmaxv) / GAMMA_F);
        float dd = dn + delta;
        float4 o4;
        o4.x = (nr + delta) / dd;
        o4.y = (ng + delta) / dd;
        o4.z = (nb + delta) / dd;
        o4.w = 1.0f - ap;
        *reinterpret_cast<float4*>(&out[((size_t)b * NPIX + p) * 4]) = o4;
    }
}

extern "C" void kernel_launch(void* const* d_in, const int* in_sizes, int n_in,
                              void* d_out, int out_size, void* d_ws, size_t ws_size,
                              hipStream_t stream) {
    const float* mpos   = (const float*)d_in[0];
    const float* mrot   = (const float*)d_in[1];
    const float* mscale = (const float*)d_in[2];
    const float* cpos   = (const float*)d_in[3];
    const float* crot   = (const float*)d_in[4];
    const float* verts  = (const float*)d_in[5];
    const int*   faces  = (const int*)d_in[6];
    const float* vcol   = (const float*)d_in[7];
    float*       out    = (float*)d_out;

    const int B  = in_sizes[3] / 3;                 // cam_pos is (B,3)
    const int BF = B * NF;
    const size_t base_bytes  = (size_t)BF * 7 * sizeof(float4);      // bbox+geo+col
    const size_t lists_bytes = (size_t)B * NTILE * NF * sizeof(unsigned short);
    const size_t cnts_bytes  = (size_t)B * NTILE * sizeof(int);
    const size_t need_full   = base_bytes + lists_bytes + cnts_bytes;

    float4* wsf = (float4*)d_ws;
    if (ws_size >= need_full) {
        unsigned short* lists = (unsigned short*)((char*)d_ws + base_bytes);
        int* cnts = (int*)((char*)d_ws + base_bytes + lists_bytes);
        stage_kernel<<<dim3(B * MM), dim3(256), 0, stream>>>(
            mpos, mrot, mscale, cpos, crot, verts, faces, vcol, wsf);
        bin_kernel<<<dim3((B * NTILE) / 4), dim3(256), 0, stream>>>(
            wsf, lists, cnts, B);
        render_tile_kernel<<<dim3(B * NTILE * 16), dim3(256), 0, stream>>>(
            wsf, lists, cnts, out, B);
    } else {
        stage_kernel<<<dim3(B * MM), dim3(256), 0, stream>>>(
            mpos, mrot, mscale, cpos, crot, verts, faces, vcol, wsf);
        render_wave_kernel<<<dim3(B * (NPIX / 4)), dim3(256), 0, stream>>>(
            wsf, out, B);
    }
}